// Round 1
// baseline (1355.088 us; speedup 1.0000x reference)
//
#include <hip/hip_runtime.h>
#include <math.h>

#define NN 50000
#define NE 800000
#define NEG 0.2f
#define EPS_BN 1e-5f

__device__ __forceinline__ float lrelu(float x){ return x > 0.f ? x : NEG * x; }

// ---------------- CSR build ----------------
__global__ __launch_bounds__(256) void k_deg_easum(const int* __restrict__ dst, const float* __restrict__ ea,
                                                   int* __restrict__ deg, float* __restrict__ easum){
  int e = blockIdx.x * 256 + threadIdx.x;
  if (e >= NE) return;
  int d = dst[e];
  atomicAdd(&deg[d], 1);
  atomicAdd(&easum[d*3+0], ea[e*3+0]);
  atomicAdd(&easum[d*3+1], ea[e*3+1]);
  atomicAdd(&easum[d*3+2], ea[e*3+2]);
}

__global__ __launch_bounds__(1024) void k_scan(const int* __restrict__ deg, int* __restrict__ rowptr){
  __shared__ int sums[1024];
  const int CHUNK = (NN + 1023) / 1024;
  int t = threadIdx.x;
  int base = t * CHUNK;
  int s = 0;
  for (int i = 0; i < CHUNK; i++){ int idx = base + i; if (idx < NN) s += deg[idx]; }
  sums[t] = s; __syncthreads();
  for (int off = 1; off < 1024; off <<= 1){
    int v = (t >= off) ? sums[t - off] : 0;
    __syncthreads();
    sums[t] += v;
    __syncthreads();
  }
  int run = (t == 0) ? 0 : sums[t - 1];
  for (int i = 0; i < CHUNK; i++){ int idx = base + i; if (idx < NN){ rowptr[idx] = run; run += deg[idx]; } }
  if (t == 0) rowptr[NN] = NE;
}

__global__ __launch_bounds__(256) void k_fill(const int* __restrict__ src, const int* __restrict__ dst,
                                              const float* __restrict__ ea, const int* __restrict__ rowptr,
                                              int* __restrict__ cnt, int* __restrict__ srcs, float* __restrict__ eas){
  int e = blockIdx.x * 256 + threadIdx.x;
  if (e >= NE) return;
  int d = dst[e];
  int pos = rowptr[d] + atomicAdd(&cnt[d], 1);
  srcs[pos] = src[e];
  eas[pos*3+0] = ea[e*3+0];
  eas[pos*3+1] = ea[e*3+1];
  eas[pos*3+2] = ea[e*3+2];
}

// ---------------- input projection ----------------
__global__ __launch_bounds__(256) void k_proj(const float* __restrict__ x, const float* __restrict__ Wp,
                                              const float* __restrict__ bp, float* __restrict__ h0){
  int i = blockIdx.x * 256 + threadIdx.x;
  if (i >= NN * 64) return;
  int n = i >> 6, c = i & 63;
  h0[i] = fmaf(x[n*2+0], Wp[c], fmaf(x[n*2+1], Wp[64+c], bp[c]));
}

// ---------------- BatchNorm (training stats) + ELU ----------------
template<int F>
__global__ void k_bn_stats(const float* __restrict__ x, float* __restrict__ sum, float* __restrict__ sq){
  int t = threadIdx.x;  // blockDim == F
  float s = 0.f, s2 = 0.f;
  for (int n = blockIdx.x; n < NN; n += gridDim.x){
    float v = x[(long)n * F + t];
    s += v; s2 += v * v;
  }
  atomicAdd(&sum[t], s);
  atomicAdd(&sq[t], s2);
}

template<int F>
__global__ __launch_bounds__(256) void k_bn_apply(float* __restrict__ x, const float* __restrict__ sum,
                                                  const float* __restrict__ sq){
  int i = blockIdx.x * 256 + threadIdx.x;
  if (i >= NN * F) return;
  int f = i % F;
  float mu = sum[f] * (1.f / NN);
  float var = sq[f] * (1.f / NN) - mu * mu;
  float w = rsqrtf(var + EPS_BN);
  float v = (x[i] - mu) * w;
  x[i] = v > 0.f ? v : expm1f(v);
}

// ---------------- g[d][h] = sum_c We[d, h*64+c] * ae[h,c] ----------------
template<int H>
__global__ void k_edge_g(const float* __restrict__ We, const float* __restrict__ ae, float* __restrict__ g){
  int t = threadIdx.x;              // blockDim = H*64
  int h = t >> 6, c = t & 63;
  float a = ae[t];
  for (int d = 0; d < 3; d++){
    float p = We[d * (H*64) + t] * a;
    for (int off = 32; off; off >>= 1) p += __shfl_down(p, off, 64);
    if (c == 0) g[d * H + h] = p;
  }
  (void)h;
}

// ---------------- GEMM: C[N,J] = A[N,K] @ B[K,J] ----------------
template<int K, int J, int TM>
__global__ __launch_bounds__(J) void k_gemm(const float* __restrict__ A, const float* __restrict__ B,
                                            float* __restrict__ C){
  __shared__ float As[TM][K];
  int row0 = blockIdx.x * TM;
  int t = threadIdx.x;  // blockDim == J
  for (int i = t; i < TM * K; i += J){
    int m = i / K, k = i % K;
    int r = row0 + m;
    As[m][k] = (r < NN) ? A[(long)r * K + k] : 0.f;
  }
  __syncthreads();
  float acc[TM];
#pragma unroll
  for (int m = 0; m < TM; m++) acc[m] = 0.f;
  for (int k = 0; k < K; k++){
    float w = B[k * J + t];
#pragma unroll
    for (int m = 0; m < TM; m++) acc[m] = fmaf(As[m][k], w, acc[m]);
  }
  for (int m = 0; m < TM; m++){
    int r = row0 + m;
    if (r < NN) C[(long)r * J + t] = acc[m];
  }
}

// ---------------- per-node attention coefficients ----------------
template<int H>
__global__ void k_attn(const float* __restrict__ hh, const float* __restrict__ asrc,
                       const float* __restrict__ adst, float* __restrict__ aS, float* __restrict__ aD){
  int n = blockIdx.x;
  int t = threadIdx.x;              // blockDim = H*64
  int h = t >> 6, c = t & 63;
  float v = hh[(long)n * (H*64) + t];
  float ps = v * asrc[t];
  float pd = v * adst[t];
  for (int off = 32; off; off >>= 1){
    ps += __shfl_down(ps, off, 64);
    pd += __shfl_down(pd, off, 64);
  }
  if (c == 0){ aS[n * H + h] = ps; aD[n * H + h] = pd; }
}

// ---------------- fused per-node segment softmax + aggregation ----------------
template<int H, bool ELU>
__global__ void k_gat(const int* __restrict__ rowptr, const int* __restrict__ srcs,
                      const float* __restrict__ eas, const int* __restrict__ deg,
                      const float* __restrict__ easum,
                      const float* __restrict__ aS, const float* __restrict__ aD,
                      const float* __restrict__ g, const float* __restrict__ hh,
                      const float* __restrict__ bias, float* __restrict__ out){
  constexpr int W = H * 64;
  int n = blockIdx.x;
  int t = threadIdx.x;              // blockDim = W
  int h = t >> 6, c = t & 63;
  int start = rowptr[n], end = rowptr[n + 1];
  float g0 = g[0*H + h], g1 = g[1*H + h], g2 = g[2*H + h];
  float adn = aD[n*H + h];
  float asn = aS[n*H + h];
  // self-loop (fill_value='mean')
  float dg = (float)deg[n];
  float inv = 1.f / fmaxf(dg, 1.f);
  float ll = asn + adn + g0 * (easum[n*3+0]*inv) + g1 * (easum[n*3+1]*inv) + g2 * (easum[n*3+2]*inv);
  ll = lrelu(ll);
  // phase 1: online max/denominator per head (lanes stride edges)
  float m = -INFINITY, den = 0.f;
  for (int pos = start + c; pos < end; pos += 64){
    int s = srcs[pos];
    float lg = aS[s*H + h] + adn + g0*eas[pos*3+0] + g1*eas[pos*3+1] + g2*eas[pos*3+2];
    lg = lrelu(lg);
    if (lg > m){ den = den * __expf(m - lg) + 1.f; m = lg; }
    else den += __expf(lg - m);
  }
  for (int off = 32; off; off >>= 1){
    float m2 = __shfl_down(m, off, 64);
    float d2 = __shfl_down(den, off, 64);
    if (m2 > m){ den = den * __expf(m - m2) + d2; m = m2; }
    else if (d2 > 0.f) den += d2 * __expf(m2 - m);
  }
  __shared__ float sm[H], sden[H];
  if (c == 0){
    float mf = fmaxf(m, ll);
    float df = den * __expf(m - mf) + __expf(ll - mf);
    sm[h] = mf;
    sden[h] = 1.f / (df + 1e-16f);
  }
  __syncthreads();
  float mf = sm[h], invden = sden[h];
  // phase 2: weighted aggregation, thread t owns output channel t
  float acc = 0.f;
  for (int pos = start; pos < end; pos++){
    int s = srcs[pos];
    float lg = aS[s*H + h] + adn + g0*eas[pos*3+0] + g1*eas[pos*3+1] + g2*eas[pos*3+2];
    lg = lrelu(lg);
    float alpha = __expf(lg - mf) * invden;
    acc = fmaf(alpha, hh[(long)s * W + t], acc);
  }
  float al = __expf(ll - mf) * invden;
  acc = fmaf(al, hh[(long)n * W + t], acc);
  acc += bias[t];
  if (ELU) acc = acc > 0.f ? acc : expm1f(acc);
  out[(long)n * W + t] = acc;
}

// ---------------- final linear 64->4 + softmax ----------------
__global__ __launch_bounds__(64) void k_final(const float* __restrict__ h3, const float* __restrict__ Wc,
                                              const float* __restrict__ bc, float* __restrict__ out){
  int n = blockIdx.x;
  int c = threadIdx.x;  // 64
  float v = h3[(long)n * 64 + c];
  float r0 = v * Wc[c*4+0], r1 = v * Wc[c*4+1], r2 = v * Wc[c*4+2], r3 = v * Wc[c*4+3];
  for (int off = 32; off; off >>= 1){
    r0 += __shfl_down(r0, off, 64);
    r1 += __shfl_down(r1, off, 64);
    r2 += __shfl_down(r2, off, 64);
    r3 += __shfl_down(r3, off, 64);
  }
  if (c == 0){
    r0 += bc[0]; r1 += bc[1]; r2 += bc[2]; r3 += bc[3];
    float mm = fmaxf(fmaxf(r0, r1), fmaxf(r2, r3));
    float e0 = __expf(r0 - mm), e1 = __expf(r1 - mm), e2 = __expf(r2 - mm), e3 = __expf(r3 - mm);
    float is = 1.f / (e0 + e1 + e2 + e3);
    out[n*4+0] = e0 * is; out[n*4+1] = e1 * is; out[n*4+2] = e2 * is; out[n*4+3] = e3 * is;
  }
}

extern "C" void kernel_launch(void* const* d_in, const int* in_sizes, int n_in,
                              void* d_out, int out_size, void* d_ws, size_t ws_size,
                              hipStream_t stream){
  const float* x   = (const float*)d_in[0];
  const int*   ei  = (const int*)d_in[1];
  const float* ea  = (const float*)d_in[2];
  const float* Wp  = (const float*)d_in[3];
  const float* bp  = (const float*)d_in[4];
  const float* W1  = (const float*)d_in[5];
  const float* as1 = (const float*)d_in[6];
  const float* ad1 = (const float*)d_in[7];
  const float* We1 = (const float*)d_in[8];
  const float* ae1 = (const float*)d_in[9];
  const float* b1  = (const float*)d_in[10];
  const float* W2  = (const float*)d_in[11];
  const float* as2 = (const float*)d_in[12];
  const float* ad2 = (const float*)d_in[13];
  const float* We2 = (const float*)d_in[14];
  const float* ae2 = (const float*)d_in[15];
  const float* b2  = (const float*)d_in[16];
  const float* W3  = (const float*)d_in[17];
  const float* as3 = (const float*)d_in[18];
  const float* ad3 = (const float*)d_in[19];
  const float* We3 = (const float*)d_in[20];
  const float* ae3 = (const float*)d_in[21];
  const float* b3  = (const float*)d_in[22];
  const float* Wc  = (const float*)d_in[23];
  const float* bc  = (const float*)d_in[24];
  const int* srcI = ei;
  const int* dstI = ei + NE;

  char* base = (char*)d_ws;
  size_t off = 0;
  auto alloc = [&](size_t bytes) -> void* {
    void* p = base + off;
    off += (bytes + 255) & ~(size_t)255;
    return p;
  };
  float* bufA  = (float*)alloc((size_t)NN * 256 * 4);
  float* bufB  = (float*)alloc((size_t)NN * 256 * 4);
  int*   deg   = (int*)  alloc((size_t)NN * 4);
  int*   cnt   = (int*)  alloc((size_t)NN * 4);
  int*   rowptr= (int*)  alloc((size_t)(NN + 1) * 4);
  int*   srcs  = (int*)  alloc((size_t)NE * 4);
  float* eas   = (float*)alloc((size_t)NE * 3 * 4);
  float* easum = (float*)alloc((size_t)NN * 3 * 4);
  float* aS    = (float*)alloc((size_t)NN * 4 * 4);
  float* aD    = (float*)alloc((size_t)NN * 4 * 4);
  float* g     = (float*)alloc(256);
  float* bsum  = (float*)alloc(256 * 4);
  float* bsq   = (float*)alloc(256 * 4);
  (void)ws_size; (void)in_sizes; (void)n_in; (void)out_size;

  // CSR build (shared by all layers)
  hipMemsetAsync(deg, 0, (size_t)NN * 4, stream);
  hipMemsetAsync(cnt, 0, (size_t)NN * 4, stream);
  hipMemsetAsync(easum, 0, (size_t)NN * 3 * 4, stream);
  k_deg_easum<<<(NE + 255) / 256, 256, 0, stream>>>(dstI, ea, deg, easum);
  k_scan<<<1, 1024, 0, stream>>>(deg, rowptr);
  k_fill<<<(NE + 255) / 256, 256, 0, stream>>>(srcI, dstI, ea, rowptr, cnt, srcs, eas);

  // input projection + BN + ELU
  k_proj<<<(NN * 64 + 255) / 256, 256, 0, stream>>>(x, Wp, bp, bufA);
  hipMemsetAsync(bsum, 0, 256 * 4, stream);
  hipMemsetAsync(bsq, 0, 256 * 4, stream);
  k_bn_stats<64><<<512, 64, 0, stream>>>(bufA, bsum, bsq);
  k_bn_apply<64><<<(NN * 64 + 255) / 256, 256, 0, stream>>>(bufA, bsum, bsq);

  // ---- GAT layer 1 (64 -> 4x64) ----
  k_edge_g<4><<<1, 256, 0, stream>>>(We1, ae1, g);
  k_gemm<64, 256, 16><<<(NN + 15) / 16, 256, 0, stream>>>(bufA, W1, bufB);
  k_attn<4><<<NN, 256, 0, stream>>>(bufB, as1, ad1, aS, aD);
  k_gat<4, false><<<NN, 256, 0, stream>>>(rowptr, srcs, eas, deg, easum, aS, aD, g, bufB, b1, bufA);
  hipMemsetAsync(bsum, 0, 256 * 4, stream);
  hipMemsetAsync(bsq, 0, 256 * 4, stream);
  k_bn_stats<256><<<512, 256, 0, stream>>>(bufA, bsum, bsq);
  k_bn_apply<256><<<(NN * 256 + 255) / 256, 256, 0, stream>>>(bufA, bsum, bsq);

  // ---- GAT layer 2 (256 -> 4x64) ----
  k_edge_g<4><<<1, 256, 0, stream>>>(We2, ae2, g);
  k_gemm<256, 256, 16><<<(NN + 15) / 16, 256, 0, stream>>>(bufA, W2, bufB);
  k_attn<4><<<NN, 256, 0, stream>>>(bufB, as2, ad2, aS, aD);
  k_gat<4, false><<<NN, 256, 0, stream>>>(rowptr, srcs, eas, deg, easum, aS, aD, g, bufB, b2, bufA);
  hipMemsetAsync(bsum, 0, 256 * 4, stream);
  hipMemsetAsync(bsq, 0, 256 * 4, stream);
  k_bn_stats<256><<<512, 256, 0, stream>>>(bufA, bsum, bsq);
  k_bn_apply<256><<<(NN * 256 + 255) / 256, 256, 0, stream>>>(bufA, bsum, bsq);

  // ---- GAT layer 3 (256 -> 1x64), ELU fused, no BN ----
  k_edge_g<1><<<1, 64, 0, stream>>>(We3, ae3, g);
  k_gemm<256, 64, 16><<<(NN + 15) / 16, 64, 0, stream>>>(bufA, W3, bufB);
  k_attn<1><<<NN, 64, 0, stream>>>(bufB, as3, ad3, aS, aD);
  k_gat<1, true><<<NN, 64, 0, stream>>>(rowptr, srcs, eas, deg, easum, aS, aD, g, bufB, b3, bufA);

  // ---- classifier + softmax ----
  k_final<<<NN, 64, 0, stream>>>(bufA, Wc, bc, (float*)d_out);
}

// Round 2
// 1150.517 us; speedup vs baseline: 1.1778x; 1.1778x over previous
//
#include <hip/hip_runtime.h>
#include <math.h>

#define NN 50000
#define NE 800000
#define NEG 0.2f
#define EPS_BN 1e-5f

__device__ __forceinline__ float lrelu(float x){ return x > 0.f ? x : NEG * x; }

// ---------------- CSR build ----------------
__global__ __launch_bounds__(256) void k_deg_easum(const int* __restrict__ dst, const float* __restrict__ ea,
                                                   int* __restrict__ deg, float* __restrict__ easum){
  int e = blockIdx.x * 256 + threadIdx.x;
  if (e >= NE) return;
  int d = dst[e];
  atomicAdd(&deg[d], 1);
  atomicAdd(&easum[d*3+0], ea[e*3+0]);
  atomicAdd(&easum[d*3+1], ea[e*3+1]);
  atomicAdd(&easum[d*3+2], ea[e*3+2]);
}

__global__ __launch_bounds__(1024) void k_scan(const int* __restrict__ deg, int* __restrict__ rowptr){
  __shared__ int sums[1024];
  const int CHUNK = (NN + 1023) / 1024;
  int t = threadIdx.x;
  int base = t * CHUNK;
  int s = 0;
  for (int i = 0; i < CHUNK; i++){ int idx = base + i; if (idx < NN) s += deg[idx]; }
  sums[t] = s; __syncthreads();
  for (int off = 1; off < 1024; off <<= 1){
    int v = (t >= off) ? sums[t - off] : 0;
    __syncthreads();
    sums[t] += v;
    __syncthreads();
  }
  int run = (t == 0) ? 0 : sums[t - 1];
  for (int i = 0; i < CHUNK; i++){ int idx = base + i; if (idx < NN){ rowptr[idx] = run; run += deg[idx]; } }
  if (t == 0) rowptr[NN] = NE;
}

__global__ __launch_bounds__(256) void k_fill(const int* __restrict__ src, const int* __restrict__ dst,
                                              const float* __restrict__ ea, const int* __restrict__ rowptr,
                                              int* __restrict__ cnt, int* __restrict__ srcs, float* __restrict__ eas){
  int e = blockIdx.x * 256 + threadIdx.x;
  if (e >= NE) return;
  int d = dst[e];
  int pos = rowptr[d] + atomicAdd(&cnt[d], 1);
  srcs[pos] = src[e];
  eas[pos*3+0] = ea[e*3+0];
  eas[pos*3+1] = ea[e*3+1];
  eas[pos*3+2] = ea[e*3+2];
}

// ---------------- input projection ----------------
__global__ __launch_bounds__(256) void k_proj(const float* __restrict__ x, const float* __restrict__ Wp,
                                              const float* __restrict__ bp, float* __restrict__ h0){
  int i = blockIdx.x * 256 + threadIdx.x;
  if (i >= NN * 64) return;
  int n = i >> 6, c = i & 63;
  h0[i] = fmaf(x[n*2+0], Wp[c], fmaf(x[n*2+1], Wp[64+c], bp[c]));
}

// ---------------- BatchNorm (training stats) + ELU ----------------
template<int F>
__global__ void k_bn_stats(const float* __restrict__ x, float* __restrict__ sum, float* __restrict__ sq){
  int t = threadIdx.x;  // blockDim == F
  float s = 0.f, s2 = 0.f;
  for (int n = blockIdx.x; n < NN; n += gridDim.x){
    float v = x[(long)n * F + t];
    s += v; s2 += v * v;
  }
  atomicAdd(&sum[t], s);
  atomicAdd(&sq[t], s2);
}

template<int F>
__global__ __launch_bounds__(256) void k_bn_apply(float* __restrict__ x, const float* __restrict__ sum,
                                                  const float* __restrict__ sq){
  int i = blockIdx.x * 256 + threadIdx.x;
  if (i >= NN * F) return;
  int f = i % F;
  float mu = sum[f] * (1.f / NN);
  float var = sq[f] * (1.f / NN) - mu * mu;
  float w = rsqrtf(var + EPS_BN);
  float v = (x[i] - mu) * w;
  x[i] = v > 0.f ? v : expm1f(v);
}

// ---------------- g[d][h] = sum_c We[d, h*64+c] * ae[h,c] ----------------
template<int H>
__global__ void k_edge_g(const float* __restrict__ We, const float* __restrict__ ae, float* __restrict__ g){
  int t = threadIdx.x;              // blockDim = H*64
  int h = t >> 6, c = t & 63;
  float a = ae[t];
  for (int d = 0; d < 3; d++){
    float p = We[d * (H*64) + t] * a;
    for (int off = 32; off; off >>= 1) p += __shfl_down(p, off, 64);
    if (c == 0) g[d * H + h] = p;
  }
  (void)h;
}

// ---------------- GEMM: C[N,J] = A[N,K] @ B[K,J] ----------------
template<int K, int J, int TM>
__global__ __launch_bounds__(J) void k_gemm(const float* __restrict__ A, const float* __restrict__ B,
                                            float* __restrict__ C){
  __shared__ float As[TM][K];
  int row0 = blockIdx.x * TM;
  int t = threadIdx.x;  // blockDim == J
  for (int i = t; i < TM * K; i += J){
    int m = i / K, k = i % K;
    int r = row0 + m;
    As[m][k] = (r < NN) ? A[(long)r * K + k] : 0.f;
  }
  __syncthreads();
  float acc[TM];
#pragma unroll
  for (int m = 0; m < TM; m++) acc[m] = 0.f;
  for (int k = 0; k < K; k++){
    float w = B[k * J + t];
#pragma unroll
    for (int m = 0; m < TM; m++) acc[m] = fmaf(As[m][k], w, acc[m]);
  }
  for (int m = 0; m < TM; m++){
    int r = row0 + m;
    if (r < NN) C[(long)r * J + t] = acc[m];
  }
}

// ---------------- per-node attention coefficients ----------------
template<int H>
__global__ void k_attn(const float* __restrict__ hh, const float* __restrict__ asrc,
                       const float* __restrict__ adst, float* __restrict__ aS, float* __restrict__ aD){
  int n = blockIdx.x;
  int t = threadIdx.x;              // blockDim = H*64
  int h = t >> 6, c = t & 63;
  float v = hh[(long)n * (H*64) + t];
  float ps = v * asrc[t];
  float pd = v * adst[t];
  for (int off = 32; off; off >>= 1){
    ps += __shfl_down(ps, off, 64);
    pd += __shfl_down(pd, off, 64);
  }
  if (c == 0){ aS[n * H + h] = ps; aD[n * H + h] = pd; }
}

// ---------------- fused per-node segment softmax + aggregation (chunked online) ----------------
// Wave h computes head-h logits once per edge (one edge/lane), keeps running
// (m, den) wave-uniform in registers, stores w=exp(l-m) + src in LDS; the
// aggregation inner loop is a single fma per thread per edge.
template<int H, bool ELU>
__global__ void k_gat(const int* __restrict__ rowptr, const int* __restrict__ srcs,
                      const float* __restrict__ eas, const int* __restrict__ deg,
                      const float* __restrict__ easum,
                      const float* __restrict__ aS, const float* __restrict__ aD,
                      const float* __restrict__ g, const float* __restrict__ hh,
                      const float* __restrict__ bias, float* __restrict__ out){
  constexpr int W = H * 64;
  int n = blockIdx.x;
  int t = threadIdx.x;              // blockDim = W, wave h = t>>6
  int h = t >> 6, c = t & 63;
  int start = rowptr[n], end = rowptr[n + 1];
  float g0 = g[0*H + h], g1 = g[1*H + h], g2 = g[2*H + h];
  float adn = aD[n*H + h];
  float asn = aS[n*H + h];

  __shared__ int   s_lds[64];
  __shared__ float w_lds[H][64];

  float m = -INFINITY, den = 0.f, acc = 0.f;

  for (int base = start; base < end; base += 64){
    int len = end - base; if (len > 64) len = 64;
    // --- per-edge logit, one edge per lane, head h per wave ---
    float l = -INFINITY;
    if (c < len){
      int pos = base + c;
      int s = srcs[pos];
      if (h == 0) s_lds[c] = s;
      float lg = aS[s*H + h] + adn + g0*eas[pos*3+0] + g1*eas[pos*3+1] + g2*eas[pos*3+2];
      l = lrelu(lg);
    }
    // wave max
    float mc = l;
#pragma unroll
    for (int off = 32; off; off >>= 1) mc = fmaxf(mc, __shfl_xor(mc, off, 64));
    float e = (c < len) ? __expf(l - mc) : 0.f;
    float sc = e;
#pragma unroll
    for (int off = 32; off; off >>= 1) sc += __shfl_xor(sc, off, 64);
    // merge into running (all values wave-uniform)
    float mn = fmaxf(m, mc);
    float r = __expf(m - mn);          // 0 when m == -inf
    den = den * r + sc * __expf(mc - mn);
    acc *= r;
    if (c < len) w_lds[h][c] = e * __expf(mc - mn);
    m = mn;
    __syncthreads();
    // --- aggregation: one fma per edge per thread ---
#pragma unroll 4
    for (int j = 0; j < len; j++){
      acc = fmaf(w_lds[h][j], hh[s_lds[j]*W + t], acc);
    }
    __syncthreads();
  }

  // self-loop (fill_value='mean')
  float dg = (float)deg[n];
  float inv = 1.f / fmaxf(dg, 1.f);
  float ll = asn + adn + g0 * (easum[n*3+0]*inv) + g1 * (easum[n*3+1]*inv) + g2 * (easum[n*3+2]*inv);
  ll = lrelu(ll);
  float mf = fmaxf(m, ll);
  float r = __expf(m - mf);
  float el = __expf(ll - mf);
  float df = den * r + el;
  acc = acc * r + el * hh[n*W + t];
  float invden = 1.f / (df + 1e-16f);
  acc = acc * invden + bias[t];
  if (ELU) acc = acc > 0.f ? acc : expm1f(acc);
  out[(long)n * W + t] = acc;
}

// ---------------- final linear 64->4 + softmax ----------------
__global__ __launch_bounds__(64) void k_final(const float* __restrict__ h3, const float* __restrict__ Wc,
                                              const float* __restrict__ bc, float* __restrict__ out){
  int n = blockIdx.x;
  int c = threadIdx.x;  // 64
  float v = h3[(long)n * 64 + c];
  float r0 = v * Wc[c*4+0], r1 = v * Wc[c*4+1], r2 = v * Wc[c*4+2], r3 = v * Wc[c*4+3];
  for (int off = 32; off; off >>= 1){
    r0 += __shfl_down(r0, off, 64);
    r1 += __shfl_down(r1, off, 64);
    r2 += __shfl_down(r2, off, 64);
    r3 += __shfl_down(r3, off, 64);
  }
  if (c == 0){
    r0 += bc[0]; r1 += bc[1]; r2 += bc[2]; r3 += bc[3];
    float mm = fmaxf(fmaxf(r0, r1), fmaxf(r2, r3));
    float e0 = __expf(r0 - mm), e1 = __expf(r1 - mm), e2 = __expf(r2 - mm), e3 = __expf(r3 - mm);
    float is = 1.f / (e0 + e1 + e2 + e3);
    out[n*4+0] = e0 * is; out[n*4+1] = e1 * is; out[n*4+2] = e2 * is; out[n*4+3] = e3 * is;
  }
}

extern "C" void kernel_launch(void* const* d_in, const int* in_sizes, int n_in,
                              void* d_out, int out_size, void* d_ws, size_t ws_size,
                              hipStream_t stream){
  const float* x   = (const float*)d_in[0];
  const int*   ei  = (const int*)d_in[1];
  const float* ea  = (const float*)d_in[2];
  const float* Wp  = (const float*)d_in[3];
  const float* bp  = (const float*)d_in[4];
  const float* W1  = (const float*)d_in[5];
  const float* as1 = (const float*)d_in[6];
  const float* ad1 = (const float*)d_in[7];
  const float* We1 = (const float*)d_in[8];
  const float* ae1 = (const float*)d_in[9];
  const float* b1  = (const float*)d_in[10];
  const float* W2  = (const float*)d_in[11];
  const float* as2 = (const float*)d_in[12];
  const float* ad2 = (const float*)d_in[13];
  const float* We2 = (const float*)d_in[14];
  const float* ae2 = (const float*)d_in[15];
  const float* b2  = (const float*)d_in[16];
  const float* W3  = (const float*)d_in[17];
  const float* as3 = (const float*)d_in[18];
  const float* ad3 = (const float*)d_in[19];
  const float* We3 = (const float*)d_in[20];
  const float* ae3 = (const float*)d_in[21];
  const float* b3  = (const float*)d_in[22];
  const float* Wc  = (const float*)d_in[23];
  const float* bc  = (const float*)d_in[24];
  const int* srcI = ei;
  const int* dstI = ei + NE;

  char* base = (char*)d_ws;
  size_t off = 0;
  auto alloc = [&](size_t bytes) -> void* {
    void* p = base + off;
    off += (bytes + 255) & ~(size_t)255;
    return p;
  };
  float* bufA  = (float*)alloc((size_t)NN * 256 * 4);
  float* bufB  = (float*)alloc((size_t)NN * 256 * 4);
  int*   deg   = (int*)  alloc((size_t)NN * 4);
  int*   cnt   = (int*)  alloc((size_t)NN * 4);
  int*   rowptr= (int*)  alloc((size_t)(NN + 1) * 4);
  int*   srcs  = (int*)  alloc((size_t)NE * 4);
  float* eas   = (float*)alloc((size_t)NE * 3 * 4);
  float* easum = (float*)alloc((size_t)NN * 3 * 4);
  float* aS    = (float*)alloc((size_t)NN * 4 * 4);
  float* aD    = (float*)alloc((size_t)NN * 4 * 4);
  float* g     = (float*)alloc(256);
  float* bsum  = (float*)alloc(256 * 4);
  float* bsq   = (float*)alloc(256 * 4);
  (void)ws_size; (void)in_sizes; (void)n_in; (void)out_size;

  // CSR build (shared by all layers)
  hipMemsetAsync(deg, 0, (size_t)NN * 4, stream);
  hipMemsetAsync(cnt, 0, (size_t)NN * 4, stream);
  hipMemsetAsync(easum, 0, (size_t)NN * 3 * 4, stream);
  k_deg_easum<<<(NE + 255) / 256, 256, 0, stream>>>(dstI, ea, deg, easum);
  k_scan<<<1, 1024, 0, stream>>>(deg, rowptr);
  k_fill<<<(NE + 255) / 256, 256, 0, stream>>>(srcI, dstI, ea, rowptr, cnt, srcs, eas);

  // input projection + BN + ELU
  k_proj<<<(NN * 64 + 255) / 256, 256, 0, stream>>>(x, Wp, bp, bufA);
  hipMemsetAsync(bsum, 0, 256 * 4, stream);
  hipMemsetAsync(bsq, 0, 256 * 4, stream);
  k_bn_stats<64><<<512, 64, 0, stream>>>(bufA, bsum, bsq);
  k_bn_apply<64><<<(NN * 64 + 255) / 256, 256, 0, stream>>>(bufA, bsum, bsq);

  // ---- GAT layer 1 (64 -> 4x64) ----
  k_edge_g<4><<<1, 256, 0, stream>>>(We1, ae1, g);
  k_gemm<64, 256, 16><<<(NN + 15) / 16, 256, 0, stream>>>(bufA, W1, bufB);
  k_attn<4><<<NN, 256, 0, stream>>>(bufB, as1, ad1, aS, aD);
  k_gat<4, false><<<NN, 256, 0, stream>>>(rowptr, srcs, eas, deg, easum, aS, aD, g, bufB, b1, bufA);
  hipMemsetAsync(bsum, 0, 256 * 4, stream);
  hipMemsetAsync(bsq, 0, 256 * 4, stream);
  k_bn_stats<256><<<512, 256, 0, stream>>>(bufA, bsum, bsq);
  k_bn_apply<256><<<(NN * 256 + 255) / 256, 256, 0, stream>>>(bufA, bsum, bsq);

  // ---- GAT layer 2 (256 -> 4x64) ----
  k_edge_g<4><<<1, 256, 0, stream>>>(We2, ae2, g);
  k_gemm<256, 256, 16><<<(NN + 15) / 16, 256, 0, stream>>>(bufA, W2, bufB);
  k_attn<4><<<NN, 256, 0, stream>>>(bufB, as2, ad2, aS, aD);
  k_gat<4, false><<<NN, 256, 0, stream>>>(rowptr, srcs, eas, deg, easum, aS, aD, g, bufB, b2, bufA);
  hipMemsetAsync(bsum, 0, 256 * 4, stream);
  hipMemsetAsync(bsq, 0, 256 * 4, stream);
  k_bn_stats<256><<<512, 256, 0, stream>>>(bufA, bsum, bsq);
  k_bn_apply<256><<<(NN * 256 + 255) / 256, 256, 0, stream>>>(bufA, bsum, bsq);

  // ---- GAT layer 3 (256 -> 1x64), ELU fused, no BN ----
  k_edge_g<1><<<1, 64, 0, stream>>>(We3, ae3, g);
  k_gemm<256, 64, 16><<<(NN + 15) / 16, 64, 0, stream>>>(bufA, W3, bufB);
  k_attn<1><<<NN, 64, 0, stream>>>(bufB, as3, ad3, aS, aD);
  k_gat<1, true><<<NN, 64, 0, stream>>>(rowptr, srcs, eas, deg, easum, aS, aD, g, bufB, b3, bufA);

  // ---- classifier + softmax ----
  k_final<<<NN, 64, 0, stream>>>(bufA, Wc, bc, (float*)d_out);
}

// Round 3
// 979.578 us; speedup vs baseline: 1.3833x; 1.1745x over previous
//
#include <hip/hip_runtime.h>
#include <math.h>

#define NN 50000
#define NE 800000
#define NEG 0.2f
#define EPS_BN 1e-5f

__device__ __forceinline__ float lrelu(float x){ return x > 0.f ? x : NEG * x; }

// ---------------- CSR build ----------------
__global__ __launch_bounds__(256) void k_deg(const int* __restrict__ dst, int* __restrict__ deg){
  int e = blockIdx.x * 256 + threadIdx.x;
  if (e >= NE) return;
  atomicAdd(&deg[dst[e]], 1);
}

__global__ __launch_bounds__(1024) void k_scan(const int* __restrict__ deg, int* __restrict__ rowptr){
  __shared__ int sums[1024];
  const int CHUNK = (NN + 1023) / 1024;
  int t = threadIdx.x;
  int base = t * CHUNK;
  int s = 0;
  for (int i = 0; i < CHUNK; i++){ int idx = base + i; if (idx < NN) s += deg[idx]; }
  sums[t] = s; __syncthreads();
  for (int off = 1; off < 1024; off <<= 1){
    int v = (t >= off) ? sums[t - off] : 0;
    __syncthreads();
    sums[t] += v;
    __syncthreads();
  }
  int run = (t == 0) ? 0 : sums[t - 1];
  for (int i = 0; i < CHUNK; i++){ int idx = base + i; if (idx < NN){ rowptr[idx] = run; run += deg[idx]; } }
  if (t == 0) rowptr[NN] = NE;
}

__global__ __launch_bounds__(256) void k_fill(const int* __restrict__ src, const int* __restrict__ dst,
                                              const float* __restrict__ ea, const int* __restrict__ rowptr,
                                              int* __restrict__ cnt, int* __restrict__ srcs, float* __restrict__ eas){
  int e = blockIdx.x * 256 + threadIdx.x;
  if (e >= NE) return;
  int d = dst[e];
  int pos = rowptr[d] + atomicAdd(&cnt[d], 1);
  srcs[pos] = src[e];
  eas[pos*3+0] = ea[e*3+0];
  eas[pos*3+1] = ea[e*3+1];
  eas[pos*3+2] = ea[e*3+2];
}

// easum[n] = sum of eas over node n's CSR segment (no atomics; 1 wave/node)
__global__ __launch_bounds__(256) void k_easum(const int* __restrict__ rowptr, const float* __restrict__ eas,
                                               float* __restrict__ easum){
  int n = blockIdx.x * 4 + (threadIdx.x >> 6);
  int c = threadIdx.x & 63;
  if (n >= NN) return;
  int start = rowptr[n], end = rowptr[n + 1];
  float s0 = 0.f, s1 = 0.f, s2 = 0.f;
  for (int p = start + c; p < end; p += 64){
    s0 += eas[p*3+0]; s1 += eas[p*3+1]; s2 += eas[p*3+2];
  }
#pragma unroll
  for (int off = 32; off; off >>= 1){
    s0 += __shfl_down(s0, off, 64);
    s1 += __shfl_down(s1, off, 64);
    s2 += __shfl_down(s2, off, 64);
  }
  if (c == 0){ easum[n*3+0] = s0; easum[n*3+1] = s1; easum[n*3+2] = s2; }
}

// ---------------- input projection ----------------
__global__ __launch_bounds__(256) void k_proj(const float* __restrict__ x, const float* __restrict__ Wp,
                                              const float* __restrict__ bp, float* __restrict__ h0){
  int i = blockIdx.x * 256 + threadIdx.x;
  if (i >= NN * 64) return;
  int n = i >> 6, c = i & 63;
  h0[i] = fmaf(x[n*2+0], Wp[c], fmaf(x[n*2+1], Wp[64+c], bp[c]));
}

// ---------------- BatchNorm (training stats) + ELU ----------------
template<int F>
__global__ void k_bn_stats(const float* __restrict__ x, float* __restrict__ sum, float* __restrict__ sq){
  int t = threadIdx.x;  // blockDim == F
  float s = 0.f, s2 = 0.f;
  for (int n = blockIdx.x; n < NN; n += gridDim.x){
    float v = x[(long)n * F + t];
    s += v; s2 += v * v;
  }
  atomicAdd(&sum[t], s);
  atomicAdd(&sq[t], s2);
}

template<int F>
__global__ __launch_bounds__(256) void k_bn_apply(float* __restrict__ x, const float* __restrict__ sum,
                                                  const float* __restrict__ sq){
  int i = blockIdx.x * 256 + threadIdx.x;
  if (i >= NN * F) return;
  int f = i % F;
  float mu = sum[f] * (1.f / NN);
  float var = sq[f] * (1.f / NN) - mu * mu;
  float w = rsqrtf(var + EPS_BN);
  float v = (x[i] - mu) * w;
  x[i] = v > 0.f ? v : expm1f(v);
}

// ---------------- g[d][h] = sum_c We[d, h*64+c] * ae[h,c] ----------------
template<int H>
__global__ void k_edge_g(const float* __restrict__ We, const float* __restrict__ ae, float* __restrict__ g){
  int t = threadIdx.x;              // blockDim = H*64
  int h = t >> 6, c = t & 63;
  float a = ae[t];
  for (int d = 0; d < 3; d++){
    float p = We[d * (H*64) + t] * a;
    for (int off = 32; off; off >>= 1) p += __shfl_down(p, off, 64);
    if (c == 0) g[d * H + h] = p;
  }
  (void)h;
}

// ---------------- GEMM: C[N,J] = A[N,K] @ B[K,J] ----------------
// 64x64 tile per 256-thread block, 4x4 acc per thread. A-tile transposed in
// LDS (ds_read_b128, 2-way conflicts = free). B read direct from global
// (<=256KB, L2-resident, wave-broadcast dedup).
template<int K, int J>
__global__ __launch_bounds__(256) void k_gemm64(const float* __restrict__ A, const float* __restrict__ B,
                                                float* __restrict__ C){
  __shared__ float As[16][68];      // [k][row], pad 68 -> 272B row stride (16B-aligned, banks +4)
  int t = threadIdx.x;
  int row0 = blockIdx.x * 64;
  int col0 = blockIdx.y * 64;
  int lr = t >> 2;                  // 0..63 : A-load row
  int lk = (t & 3) * 4;             // A-load k quad
  int tr = t >> 4;                  // 0..15 : compute row group
  int tc = t & 15;                  // 0..15 : compute col group
  const float* Bp = B + col0 + tc * 4;

  float acc[4][4];
#pragma unroll
  for (int i = 0; i < 4; i++)
#pragma unroll
    for (int j = 0; j < 4; j++) acc[i][j] = 0.f;

  for (int kt = 0; kt < K; kt += 16){
    // stage A tile (transposed)
    float4 av = make_float4(0.f, 0.f, 0.f, 0.f);
    int ar = row0 + lr;
    if (ar < NN) av = *(const float4*)&A[(long)ar * K + kt + lk];
    __syncthreads();
    As[lk+0][lr] = av.x; As[lk+1][lr] = av.y; As[lk+2][lr] = av.z; As[lk+3][lr] = av.w;
    __syncthreads();
#pragma unroll
    for (int k = 0; k < 16; k++){
      float4 a = *(const float4*)&As[k][tr*4];
      float4 b = *(const float4*)&Bp[(kt + k) * J];
      acc[0][0] = fmaf(a.x, b.x, acc[0][0]); acc[0][1] = fmaf(a.x, b.y, acc[0][1]);
      acc[0][2] = fmaf(a.x, b.z, acc[0][2]); acc[0][3] = fmaf(a.x, b.w, acc[0][3]);
      acc[1][0] = fmaf(a.y, b.x, acc[1][0]); acc[1][1] = fmaf(a.y, b.y, acc[1][1]);
      acc[1][2] = fmaf(a.y, b.z, acc[1][2]); acc[1][3] = fmaf(a.y, b.w, acc[1][3]);
      acc[2][0] = fmaf(a.z, b.x, acc[2][0]); acc[2][1] = fmaf(a.z, b.y, acc[2][1]);
      acc[2][2] = fmaf(a.z, b.z, acc[2][2]); acc[2][3] = fmaf(a.z, b.w, acc[2][3]);
      acc[3][0] = fmaf(a.w, b.x, acc[3][0]); acc[3][1] = fmaf(a.w, b.y, acc[3][1]);
      acc[3][2] = fmaf(a.w, b.z, acc[3][2]); acc[3][3] = fmaf(a.w, b.w, acc[3][3]);
    }
  }
#pragma unroll
  for (int i = 0; i < 4; i++){
    int r = row0 + tr * 4 + i;
    if (r < NN){
      float4 v = make_float4(acc[i][0], acc[i][1], acc[i][2], acc[i][3]);
      *(float4*)&C[(long)r * J + col0 + tc * 4] = v;
    }
  }
}

// ---------------- per-node attention coefficients ----------------
template<int H>
__global__ void k_attn(const float* __restrict__ hh, const float* __restrict__ asrc,
                       const float* __restrict__ adst, float* __restrict__ aS, float* __restrict__ aD){
  int n = blockIdx.x;
  int t = threadIdx.x;              // blockDim = H*64
  int h = t >> 6, c = t & 63;
  float v = hh[(long)n * (H*64) + t];
  float ps = v * asrc[t];
  float pd = v * adst[t];
  for (int off = 32; off; off >>= 1){
    ps += __shfl_down(ps, off, 64);
    pd += __shfl_down(pd, off, 64);
  }
  if (c == 0){ aS[n * H + h] = ps; aD[n * H + h] = pd; }
}

// ---------------- fused per-node segment softmax + aggregation (chunked online) ----------------
template<int H, bool ELU>
__global__ void k_gat(const int* __restrict__ rowptr, const int* __restrict__ srcs,
                      const float* __restrict__ eas, const int* __restrict__ deg,
                      const float* __restrict__ easum,
                      const float* __restrict__ aS, const float* __restrict__ aD,
                      const float* __restrict__ g, const float* __restrict__ hh,
                      const float* __restrict__ bias, float* __restrict__ out){
  constexpr int W = H * 64;
  int n = blockIdx.x;
  int t = threadIdx.x;              // blockDim = W, wave h = t>>6
  int h = t >> 6, c = t & 63;
  int start = rowptr[n], end = rowptr[n + 1];
  float g0 = g[0*H + h], g1 = g[1*H + h], g2 = g[2*H + h];
  float adn = aD[n*H + h];
  float asn = aS[n*H + h];

  __shared__ int   s_lds[64];
  __shared__ float w_lds[H][64];

  float m = -INFINITY, den = 0.f, acc = 0.f;

  for (int base = start; base < end; base += 64){
    int len = end - base; if (len > 64) len = 64;
    // --- per-edge logit, one edge per lane, head h per wave ---
    float l = -INFINITY;
    if (c < len){
      int pos = base + c;
      int s = srcs[pos];
      if (h == 0) s_lds[c] = s;
      float lg = aS[s*H + h] + adn + g0*eas[pos*3+0] + g1*eas[pos*3+1] + g2*eas[pos*3+2];
      l = lrelu(lg);
    }
    // wave max
    float mc = l;
#pragma unroll
    for (int off = 32; off; off >>= 1) mc = fmaxf(mc, __shfl_xor(mc, off, 64));
    float e = (c < len) ? __expf(l - mc) : 0.f;
    float sc = e;
#pragma unroll
    for (int off = 32; off; off >>= 1) sc += __shfl_xor(sc, off, 64);
    // merge into running (all values wave-uniform)
    float mn = fmaxf(m, mc);
    float r = __expf(m - mn);          // 0 when m == -inf
    den = den * r + sc * __expf(mc - mn);
    acc *= r;
    if (c < len) w_lds[h][c] = e * __expf(mc - mn);
    m = mn;
    __syncthreads();
    // --- aggregation: one fma per edge per thread ---
#pragma unroll 4
    for (int j = 0; j < len; j++){
      acc = fmaf(w_lds[h][j], hh[s_lds[j]*W + t], acc);
    }
    __syncthreads();
  }

  // self-loop (fill_value='mean')
  float dg = (float)deg[n];
  float inv = 1.f / fmaxf(dg, 1.f);
  float ll = asn + adn + g0 * (easum[n*3+0]*inv) + g1 * (easum[n*3+1]*inv) + g2 * (easum[n*3+2]*inv);
  ll = lrelu(ll);
  float mf = fmaxf(m, ll);
  float r = __expf(m - mf);
  float el = __expf(ll - mf);
  float df = den * r + el;
  acc = acc * r + el * hh[n*W + t];
  float invden = 1.f / (df + 1e-16f);
  acc = acc * invden + bias[t];
  if (ELU) acc = acc > 0.f ? acc : expm1f(acc);
  out[(long)n * W + t] = acc;
}

// ---------------- final linear 64->4 + softmax ----------------
__global__ __launch_bounds__(64) void k_final(const float* __restrict__ h3, const float* __restrict__ Wc,
                                              const float* __restrict__ bc, float* __restrict__ out){
  int n = blockIdx.x;
  int c = threadIdx.x;  // 64
  float v = h3[(long)n * 64 + c];
  float r0 = v * Wc[c*4+0], r1 = v * Wc[c*4+1], r2 = v * Wc[c*4+2], r3 = v * Wc[c*4+3];
  for (int off = 32; off; off >>= 1){
    r0 += __shfl_down(r0, off, 64);
    r1 += __shfl_down(r1, off, 64);
    r2 += __shfl_down(r2, off, 64);
    r3 += __shfl_down(r3, off, 64);
  }
  if (c == 0){
    r0 += bc[0]; r1 += bc[1]; r2 += bc[2]; r3 += bc[3];
    float mm = fmaxf(fmaxf(r0, r1), fmaxf(r2, r3));
    float e0 = __expf(r0 - mm), e1 = __expf(r1 - mm), e2 = __expf(r2 - mm), e3 = __expf(r3 - mm);
    float is = 1.f / (e0 + e1 + e2 + e3);
    out[n*4+0] = e0 * is; out[n*4+1] = e1 * is; out[n*4+2] = e2 * is; out[n*4+3] = e3 * is;
  }
}

extern "C" void kernel_launch(void* const* d_in, const int* in_sizes, int n_in,
                              void* d_out, int out_size, void* d_ws, size_t ws_size,
                              hipStream_t stream){
  const float* x   = (const float*)d_in[0];
  const int*   ei  = (const int*)d_in[1];
  const float* ea  = (const float*)d_in[2];
  const float* Wp  = (const float*)d_in[3];
  const float* bp  = (const float*)d_in[4];
  const float* W1  = (const float*)d_in[5];
  const float* as1 = (const float*)d_in[6];
  const float* ad1 = (const float*)d_in[7];
  const float* We1 = (const float*)d_in[8];
  const float* ae1 = (const float*)d_in[9];
  const float* b1  = (const float*)d_in[10];
  const float* W2  = (const float*)d_in[11];
  const float* as2 = (const float*)d_in[12];
  const float* ad2 = (const float*)d_in[13];
  const float* We2 = (const float*)d_in[14];
  const float* ae2 = (const float*)d_in[15];
  const float* b2  = (const float*)d_in[16];
  const float* W3  = (const float*)d_in[17];
  const float* as3 = (const float*)d_in[18];
  const float* ad3 = (const float*)d_in[19];
  const float* We3 = (const float*)d_in[20];
  const float* ae3 = (const float*)d_in[21];
  const float* b3  = (const float*)d_in[22];
  const float* Wc  = (const float*)d_in[23];
  const float* bc  = (const float*)d_in[24];
  const int* srcI = ei;
  const int* dstI = ei + NE;

  char* base = (char*)d_ws;
  size_t off = 0;
  auto alloc = [&](size_t bytes) -> void* {
    void* p = base + off;
    off += (bytes + 255) & ~(size_t)255;
    return p;
  };
  float* bufA  = (float*)alloc((size_t)NN * 256 * 4);
  float* bufB  = (float*)alloc((size_t)NN * 256 * 4);
  int*   deg   = (int*)  alloc((size_t)NN * 4);
  int*   cnt   = (int*)  alloc((size_t)NN * 4);
  int*   rowptr= (int*)  alloc((size_t)(NN + 1) * 4);
  int*   srcs  = (int*)  alloc((size_t)NE * 4);
  float* eas   = (float*)alloc((size_t)NE * 3 * 4);
  float* easum = (float*)alloc((size_t)NN * 3 * 4);
  float* aS    = (float*)alloc((size_t)NN * 4 * 4);
  float* aD    = (float*)alloc((size_t)NN * 4 * 4);
  float* g     = (float*)alloc(256);
  float* bsum  = (float*)alloc(256 * 4);
  float* bsq   = (float*)alloc(256 * 4);
  (void)ws_size; (void)in_sizes; (void)n_in; (void)out_size;

  // CSR build (shared by all layers)
  hipMemsetAsync(deg, 0, (size_t)NN * 4, stream);
  hipMemsetAsync(cnt, 0, (size_t)NN * 4, stream);
  k_deg<<<(NE + 255) / 256, 256, 0, stream>>>(dstI, deg);
  k_scan<<<1, 1024, 0, stream>>>(deg, rowptr);
  k_fill<<<(NE + 255) / 256, 256, 0, stream>>>(srcI, dstI, ea, rowptr, cnt, srcs, eas);
  k_easum<<<(NN + 3) / 4, 256, 0, stream>>>(rowptr, eas, easum);

  // input projection + BN + ELU
  k_proj<<<(NN * 64 + 255) / 256, 256, 0, stream>>>(x, Wp, bp, bufA);
  hipMemsetAsync(bsum, 0, 256 * 4, stream);
  hipMemsetAsync(bsq, 0, 256 * 4, stream);
  k_bn_stats<64><<<512, 64, 0, stream>>>(bufA, bsum, bsq);
  k_bn_apply<64><<<(NN * 64 + 255) / 256, 256, 0, stream>>>(bufA, bsum, bsq);

  // ---- GAT layer 1 (64 -> 4x64) ----
  k_edge_g<4><<<1, 256, 0, stream>>>(We1, ae1, g);
  k_gemm64<64, 256><<<dim3((NN + 63) / 64, 4), 256, 0, stream>>>(bufA, W1, bufB);
  k_attn<4><<<NN, 256, 0, stream>>>(bufB, as1, ad1, aS, aD);
  k_gat<4, false><<<NN, 256, 0, stream>>>(rowptr, srcs, eas, deg, easum, aS, aD, g, bufB, b1, bufA);
  hipMemsetAsync(bsum, 0, 256 * 4, stream);
  hipMemsetAsync(bsq, 0, 256 * 4, stream);
  k_bn_stats<256><<<512, 256, 0, stream>>>(bufA, bsum, bsq);
  k_bn_apply<256><<<(NN * 256 + 255) / 256, 256, 0, stream>>>(bufA, bsum, bsq);

  // ---- GAT layer 2 (256 -> 4x64) ----
  k_edge_g<4><<<1, 256, 0, stream>>>(We2, ae2, g);
  k_gemm64<256, 256><<<dim3((NN + 63) / 64, 4), 256, 0, stream>>>(bufA, W2, bufB);
  k_attn<4><<<NN, 256, 0, stream>>>(bufB, as2, ad2, aS, aD);
  k_gat<4, false><<<NN, 256, 0, stream>>>(rowptr, srcs, eas, deg, easum, aS, aD, g, bufB, b2, bufA);
  hipMemsetAsync(bsum, 0, 256 * 4, stream);
  hipMemsetAsync(bsq, 0, 256 * 4, stream);
  k_bn_stats<256><<<512, 256, 0, stream>>>(bufA, bsum, bsq);
  k_bn_apply<256><<<(NN * 256 + 255) / 256, 256, 0, stream>>>(bufA, bsum, bsq);

  // ---- GAT layer 3 (256 -> 1x64), ELU fused, no BN ----
  k_edge_g<1><<<1, 64, 0, stream>>>(We3, ae3, g);
  k_gemm64<256, 64><<<dim3((NN + 63) / 64, 1), 256, 0, stream>>>(bufA, W3, bufB);
  k_attn<1><<<NN, 64, 0, stream>>>(bufB, as3, ad3, aS, aD);
  k_gat<1, true><<<NN, 64, 0, stream>>>(rowptr, srcs, eas, deg, easum, aS, aD, g, bufB, b3, bufA);

  // ---- classifier + softmax ----
  k_final<<<NN, 64, 0, stream>>>(bufA, Wc, bc, (float*)d_out);
}